// Round 1
// baseline (122.775 us; speedup 1.0000x reference)
//
#include <hip/hip_runtime.h>
#include <math.h>

// SinkhornWarpInterpolator: fused single-kernel implementation.
// B=16, C=4, H=W=256, PATCH=4 -> 64x64 tokens of dim 64, WIN=8 ->
// 8x8 windows/image -> 1024 windows, 64 tokens/window, 64x64 plan.
// Linear-domain Sinkhorn (mathematically == log-domain reference).

#define S0 68   // LDS row stride in floats (16B aligned, bank-spreading)

__global__ __launch_bounds__(256, 4)
void skw_kernel(const float* __restrict__ z0, const float* __restrict__ z1,
                float* __restrict__ out) {
    __shared__ float f0[64 * S0];       // token-major features of z0; reused as M
    __shared__ float f1t[64 * S0];      // d-major (transposed) features of z1
    __shared__ float psq[256];
    __shared__ float invn0[64], invn1[64];
    __shared__ float redbuf[256];
    __shared__ float rowr[64], colr[64];
    __shared__ float dispx[64], dispy[64];

    const int t  = threadIdx.x;
    const int blk = blockIdx.x;
    const int b  = blk >> 6;
    const int wy = (blk >> 3) & 7;
    const int wx = blk & 7;
    const int Y0 = wy * 32, X0 = wx * 32;

    // staging geometry: thread -> (row-in-window yy, float4-column xq)
    const int xq = t & 7;          // token col within window == float4 index
    const int yy = (t >> 3) & 31;  // pixel row within window
    const int mm = (yy >> 2) * 8 + xq;  // token index in window
    const int pi = yy & 3;              // row within patch

    // ---- stage z0 -> f0 (token-major), per-thread partial sum of squares ----
    {
        float a = 0.f;
        const float* src = z0 + (size_t)(b * 4) * 65536 + (size_t)(Y0 + yy) * 256 + X0 + xq * 4;
        #pragma unroll
        for (int c = 0; c < 4; ++c) {
            float4 v = *(const float4*)(src + c * 65536);
            a += v.x*v.x + v.y*v.y + v.z*v.z + v.w*v.w;
            *(float4*)&f0[mm * S0 + c * 16 + pi * 4] = v;
        }
        psq[t] = a;
    }
    __syncthreads();
    if (t < 64) {
        const int ti = t >> 3, tj = t & 7;
        float s = psq[(ti*4+0)*8+tj] + psq[(ti*4+1)*8+tj]
                + psq[(ti*4+2)*8+tj] + psq[(ti*4+3)*8+tj];
        invn0[t] = 1.0f / fmaxf(sqrtf(s), 1e-6f);
    }
    __syncthreads();
    // ---- stage z1 -> f1t (d-major / transposed) ----
    {
        float a = 0.f;
        const float* src = z1 + (size_t)(b * 4) * 65536 + (size_t)(Y0 + yy) * 256 + X0 + xq * 4;
        #pragma unroll
        for (int c = 0; c < 4; ++c) {
            float4 v = *(const float4*)(src + c * 65536);
            a += v.x*v.x + v.y*v.y + v.z*v.z + v.w*v.w;
            const int d = c * 16 + pi * 4;
            f1t[(d+0)*S0 + mm] = v.x;
            f1t[(d+1)*S0 + mm] = v.y;
            f1t[(d+2)*S0 + mm] = v.z;
            f1t[(d+3)*S0 + mm] = v.w;
        }
        psq[t] = a;
    }
    __syncthreads();
    if (t < 64) {
        const int ti = t >> 3, tj = t & 7;
        float s = psq[(ti*4+0)*8+tj] + psq[(ti*4+1)*8+tj]
                + psq[(ti*4+2)*8+tj] + psq[(ti*4+3)*8+tj];
        invn1[t] = 1.0f / fmaxf(sqrtf(s), 1e-6f);
    }
    __syncthreads();

    // ---- logits GEMM: 4x4 output block per thread, accumulators in regs ----
    const int bi = t >> 4, bj = t & 15;
    float acc[4][4];
    #pragma unroll
    for (int r = 0; r < 4; ++r)
        #pragma unroll
        for (int s2 = 0; s2 < 4; ++s2) acc[r][s2] = 0.f;

    #pragma unroll 4
    for (int dc = 0; dc < 16; ++dc) {
        float4 A[4], Bv[4];
        #pragma unroll
        for (int r = 0; r < 4; ++r) A[r] = *(const float4*)&f0[(bi*4+r)*S0 + dc*4];
        #pragma unroll
        for (int dd = 0; dd < 4; ++dd) Bv[dd] = *(const float4*)&f1t[(dc*4+dd)*S0 + bj*4];
        #pragma unroll
        for (int r = 0; r < 4; ++r) {
            acc[r][0] += A[r].x*Bv[0].x + A[r].y*Bv[1].x + A[r].z*Bv[2].x + A[r].w*Bv[3].x;
            acc[r][1] += A[r].x*Bv[0].y + A[r].y*Bv[1].y + A[r].z*Bv[2].y + A[r].w*Bv[3].y;
            acc[r][2] += A[r].x*Bv[0].z + A[r].y*Bv[1].z + A[r].z*Bv[2].z + A[r].w*Bv[3].z;
            acc[r][3] += A[r].x*Bv[0].w + A[r].y*Bv[1].w + A[r].z*Bv[2].w + A[r].w*Bv[3].w;
        }
    }
    float si[4], sj[4];
    #pragma unroll
    for (int r = 0; r < 4; ++r) si[r] = invn0[bi*4+r] * 20.0f;   // 1/TAU == 20
    #pragma unroll
    for (int s2 = 0; s2 < 4; ++s2) sj[s2] = invn1[bj*4+s2];
    __syncthreads();               // all threads done reading f0/f1t
    float* Mm = f0;                // reuse f0 buffer for the plan matrix
    #pragma unroll
    for (int r = 0; r < 4; ++r) {
        float4 o;
        o.x = acc[r][0]*si[r]*sj[0];
        o.y = acc[r][1]*si[r]*sj[1];
        o.z = acc[r][2]*si[r]*sj[2];
        o.w = acc[r][3]*si[r]*sj[3];
        *(float4*)&Mm[(bi*4+r)*S0 + bj*4] = o;
    }
    __syncthreads();

    // ---- Sinkhorn, linear domain with deferred scaling ----
    const int ri = t >> 2, q = t & 3;
    const int cbase = q * 16;

    // row pass 1: stabilized exp + row sum (defer rowr)
    {
        float v[16];
        #pragma unroll
        for (int u = 0; u < 4; ++u) {
            float4 x = *(const float4*)&Mm[ri*S0 + cbase + u*4];
            v[u*4+0]=x.x; v[u*4+1]=x.y; v[u*4+2]=x.z; v[u*4+3]=x.w;
        }
        float mx = v[0];
        #pragma unroll
        for (int k = 1; k < 16; ++k) mx = fmaxf(mx, v[k]);
        mx = fmaxf(mx, __shfl_xor(mx, 1));
        mx = fmaxf(mx, __shfl_xor(mx, 2));
        float s = 0.f;
        #pragma unroll
        for (int k = 0; k < 16; ++k) { v[k] = __expf(v[k] - mx); s += v[k]; }
        s += __shfl_xor(s, 1);
        s += __shfl_xor(s, 2);
        #pragma unroll
        for (int u = 0; u < 4; ++u)
            *(float4*)&Mm[ri*S0 + cbase + u*4] =
                make_float4(v[u*4+0], v[u*4+1], v[u*4+2], v[u*4+3]);
        if (q == 0) rowr[ri] = 1.0f / s;
    }
    __syncthreads();

    for (int it = 0; it < 20; ++it) {
        // col pass: apply pending rowr, write back, defer colr
        {
            const int j = t & 63, g = t >> 6;
            float part = 0.f;
            #pragma unroll
            for (int k = 0; k < 16; ++k) {
                const int i = g * 16 + k;
                float v = Mm[i*S0 + j] * rowr[i];
                Mm[i*S0 + j] = v;
                part += v;
            }
            redbuf[g*64 + j] = part;
        }
        __syncthreads();
        if (t < 64)
            colr[t] = 1.0f / (redbuf[t] + redbuf[64+t] + redbuf[128+t] + redbuf[192+t]);
        __syncthreads();
        if (it < 19) {
            // row pass: apply pending colr, write back, defer rowr
            float v[16], s = 0.f;
            #pragma unroll
            for (int u = 0; u < 4; ++u) {
                float4 x = *(const float4*)&Mm[ri*S0 + cbase + u*4];
                float4 c = *(const float4*)&colr[cbase + u*4];
                x.x *= c.x; x.y *= c.y; x.z *= c.z; x.w *= c.w;
                v[u*4+0]=x.x; v[u*4+1]=x.y; v[u*4+2]=x.z; v[u*4+3]=x.w;
                s += x.x + x.y + x.z + x.w;
            }
            s += __shfl_xor(s, 1);
            s += __shfl_xor(s, 2);
            #pragma unroll
            for (int u = 0; u < 4; ++u)
                *(float4*)&Mm[ri*S0 + cbase + u*4] =
                    make_float4(v[u*4+0], v[u*4+1], v[u*4+2], v[u*4+3]);
            if (q == 0) rowr[ri] = 1.0f / s;
            __syncthreads();
        }
    }

    // ---- final row softmax fused with expected-position reduction ----
    {
        float s = 0.f, sx = 0.f, sy = 0.f;
        #pragma unroll
        for (int u = 0; u < 4; ++u) {
            float4 x = *(const float4*)&Mm[ri*S0 + cbase + u*4];
            float4 c = *(const float4*)&colr[cbase + u*4];
            float vv[4] = {x.x*c.x, x.y*c.y, x.z*c.z, x.w*c.w};
            #pragma unroll
            for (int k = 0; k < 4; ++k) {
                const int j = cbase + u*4 + k;
                s  += vv[k];
                sx += vv[k] * (float)(j & 7);
                sy += vv[k] * (float)(j >> 3);
            }
        }
        s  += __shfl_xor(s, 1);  s  += __shfl_xor(s, 2);
        sx += __shfl_xor(sx, 1); sx += __shfl_xor(sx, 2);
        sy += __shfl_xor(sy, 1); sy += __shfl_xor(sy, 2);
        if (q == 0) {
            const float inv = 1.0f / s;
            dispx[ri] = sx * inv - (float)(ri & 7);
            dispy[ri] = sy * inv - (float)(ri >> 3);
        }
    }
    __syncthreads();

    // ---- warp: bilinear border sample of z1 at (pos + 4*disp) ----
    #pragma unroll
    for (int rep = 0; rep < 4; ++rep) {
        const int p = rep * 256 + t;
        const int y = p >> 5, x = p & 31;
        const int m2 = (y >> 2) * 8 + (x >> 2);
        float gx = (float)(X0 + x) + 4.0f * dispx[m2];
        float gy = (float)(Y0 + y) + 4.0f * dispy[m2];
        gx = fminf(fmaxf(gx, 0.0f), 255.0f);
        gy = fminf(fmaxf(gy, 0.0f), 255.0f);
        const float x0f = floorf(gx), y0f = floorf(gy);
        const float wxf = gx - x0f, wyf = gy - y0f;
        int xi0 = (int)x0f, yi0 = (int)y0f;
        const int xi1 = min(xi0 + 1, 255), yi1 = min(yi0 + 1, 255);
        const float w00 = (1.f-wxf)*(1.f-wyf), w01 = wxf*(1.f-wyf);
        const float w10 = (1.f-wxf)*wyf,       w11 = wxf*wyf;
        const float* basep = z1 + (size_t)(b * 4) * 65536;
        #pragma unroll
        for (int c = 0; c < 4; ++c) {
            const float* pc = basep + c * 65536;
            const float v00 = pc[yi0*256 + xi0], v01 = pc[yi0*256 + xi1];
            const float v10 = pc[yi1*256 + xi0], v11 = pc[yi1*256 + xi1];
            out[((size_t)(b*4+c)*256 + (Y0+y))*256 + X0 + x]
                = v00*w00 + v01*w01 + v10*w10 + v11*w11;
        }
    }
}

extern "C" void kernel_launch(void* const* d_in, const int* in_sizes, int n_in,
                              void* d_out, int out_size, void* d_ws, size_t ws_size,
                              hipStream_t stream) {
    (void)in_sizes; (void)n_in; (void)d_ws; (void)ws_size; (void)out_size;
    const float* z0 = (const float*)d_in[0];
    const float* z1 = (const float*)d_in[1];
    float* out = (float*)d_out;
    // 16 images * 8*8 windows = 1024 blocks, 256 threads each
    skw_kernel<<<dim3(1024), dim3(256), 0, stream>>>(z0, z1, out);
}

// Round 4
// 107.954 us; speedup vs baseline: 1.1373x; 1.1373x over previous
//
#include <hip/hip_runtime.h>
#include <math.h>

// SinkhornWarpInterpolator, v2: register-resident Sinkhorn.
// 256 blocks x 256 threads; block = (image b, window-row wy, half-row wxq)
// covering 4 windows of 8x8 tokens (32x32 px each). Phases:
//  1) per window: stage features -> LDS, collaborative 64x64x64 GEMM -> M_w
//  2) per wave w: load K=exp(M_w) rows + cols into 128 VGPRs
//  3) factored Sinkhorn u=1/(Kv), v=1/(K^T u): pure VALU, no LDS, no barriers
//  4) expected-position flow -> bilinear border warp of z1

#define S0 68   // LDS row stride in floats (16B aligned)

__device__ __forceinline__ float rlane(float v, int l) {
    return __uint_as_float(__builtin_amdgcn_readlane(__float_as_uint(v), l));
}

__global__ __launch_bounds__(256, 1)
void skw_kernel(const float* __restrict__ z0, const float* __restrict__ z1,
                float* __restrict__ out) {
    __shared__ float f0 [64 * S0];        // token-major features of z0 (reused per window)
    __shared__ float f1t[64 * S0];        // d-major features of z1 (reused per window)
    __shared__ float Mw [4 * 64 * S0];    // scaled logits, one buffer per window
    __shared__ float psq0[256], psq1[256];
    __shared__ float invn0[64], invn1[64];
    __shared__ float dispxA[256], dispyA[256];

    const int t   = threadIdx.x;
    const int blk = blockIdx.x;            // 256 blocks
    const int b   = blk >> 4;              // image 0..15
    const int wy  = (blk >> 1) & 7;        // window row 0..7
    const int wxq = blk & 1;               // half-row 0..1
    const int Y0  = wy * 32;
    const int XB  = wxq * 128;             // x base of the 4-window strip

    // staging geometry
    const int xq = t & 7;                  // float4 column within 32 px
    const int yy = (t >> 3) & 31;          // pixel row within window
    const int mm = (yy >> 2) * 8 + xq;     // token index
    const int pi = yy & 3;                 // row within patch

    const int wv   = t >> 6;               // wave id == this wave's window
    const int lane = t & 63;

    // ---------------- phase 1: stage + GEMM for each of the 4 windows ----------------
    #pragma unroll 1
    for (int w = 0; w < 4; ++w) {
        const int X0 = XB + w * 32;
        {
            const size_t base = (size_t)(b * 4) * 65536 + (size_t)(Y0 + yy) * 256 + X0 + xq * 4;
            const float* s0p = z0 + base;
            const float* s1p = z1 + base;
            float a0 = 0.f;
            #pragma unroll
            for (int c = 0; c < 4; ++c) {
                float4 vv = *(const float4*)(s0p + c * 65536);
                a0 += vv.x*vv.x + vv.y*vv.y + vv.z*vv.z + vv.w*vv.w;
                *(float4*)&f0[mm * S0 + c * 16 + pi * 4] = vv;
            }
            psq0[t] = a0;
            float a1 = 0.f;
            #pragma unroll
            for (int c = 0; c < 4; ++c) {
                float4 vv = *(const float4*)(s1p + c * 65536);
                a1 += vv.x*vv.x + vv.y*vv.y + vv.z*vv.z + vv.w*vv.w;
                const int d = c * 16 + pi * 4;
                f1t[(d+0)*S0 + mm] = vv.x;
                f1t[(d+1)*S0 + mm] = vv.y;
                f1t[(d+2)*S0 + mm] = vv.z;
                f1t[(d+3)*S0 + mm] = vv.w;
            }
            psq1[t] = a1;
        }
        __syncthreads();
        if (t < 128) {
            const int u2 = t & 63;
            const float* ps = (t < 64) ? psq0 : psq1;
            const int ti = u2 >> 3, tj = u2 & 7;
            float s = ps[(ti*4+0)*8+tj] + ps[(ti*4+1)*8+tj]
                    + ps[(ti*4+2)*8+tj] + ps[(ti*4+3)*8+tj];
            float r = 1.0f / fmaxf(sqrtf(s), 1e-6f);
            if (t < 64) invn0[u2] = r; else invn1[u2] = r;
        }
        __syncthreads();

        // collaborative GEMM: 4x4 block per thread
        const int bi = t >> 4, bj = t & 15;
        float acc[4][4];
        #pragma unroll
        for (int r = 0; r < 4; ++r)
            #pragma unroll
            for (int s2 = 0; s2 < 4; ++s2) acc[r][s2] = 0.f;

        #pragma unroll 4
        for (int dc = 0; dc < 16; ++dc) {
            float4 A[4], Bv[4];
            #pragma unroll
            for (int r = 0; r < 4; ++r) A[r] = *(const float4*)&f0[(bi*4+r)*S0 + dc*4];
            #pragma unroll
            for (int dd = 0; dd < 4; ++dd) Bv[dd] = *(const float4*)&f1t[(dc*4+dd)*S0 + bj*4];
            #pragma unroll
            for (int r = 0; r < 4; ++r) {
                acc[r][0] += A[r].x*Bv[0].x + A[r].y*Bv[1].x + A[r].z*Bv[2].x + A[r].w*Bv[3].x;
                acc[r][1] += A[r].x*Bv[0].y + A[r].y*Bv[1].y + A[r].z*Bv[2].y + A[r].w*Bv[3].y;
                acc[r][2] += A[r].x*Bv[0].z + A[r].y*Bv[1].z + A[r].z*Bv[2].z + A[r].w*Bv[3].z;
                acc[r][3] += A[r].x*Bv[0].w + A[r].y*Bv[1].w + A[r].z*Bv[2].w + A[r].w*Bv[3].w;
            }
        }
        float si[4], sj[4];
        #pragma unroll
        for (int r = 0; r < 4; ++r)  si[r] = invn0[bi*4+r] * 20.0f;   // 1/TAU
        #pragma unroll
        for (int s2 = 0; s2 < 4; ++s2) sj[s2] = invn1[bj*4+s2];
        float* Mo = &Mw[w * (64 * S0)];
        #pragma unroll
        for (int r = 0; r < 4; ++r) {
            float4 o;
            o.x = acc[r][0]*si[r]*sj[0];
            o.y = acc[r][1]*si[r]*sj[1];
            o.z = acc[r][2]*si[r]*sj[2];
            o.w = acc[r][3]*si[r]*sj[3];
            *(float4*)&Mo[(bi*4+r)*S0 + bj*4] = o;
        }
        __syncthreads();   // M_w complete; f0/f1t free for next window
    }

    // ---------------- phase 2: load K (rows) and K^T (cols) for this wave's window ----------------
    const float* Mb = &Mw[wv * (64 * S0)];
    float K[64], KT[64];
    #pragma unroll
    for (int j4 = 0; j4 < 16; ++j4) {
        float4 r4 = *(const float4*)&Mb[lane * S0 + j4 * 4];
        K[4*j4+0] = __expf(r4.x); K[4*j4+1] = __expf(r4.y);
        K[4*j4+2] = __expf(r4.z); K[4*j4+3] = __expf(r4.w);
    }
    #pragma unroll
    for (int j = 0; j < 64; ++j) KT[j] = __expf(Mb[j * S0 + lane]);

    // ---------------- phase 3: factored Sinkhorn, all-register, no barriers ----------------
    float u, v;
    {
        float s0=0.f, s1=0.f, s2=0.f, s3=0.f;            // R-update #1 (v == 1)
        #pragma unroll
        for (int j = 0; j < 64; j += 4) {
            s0 += K[j]; s1 += K[j+1]; s2 += K[j+2]; s3 += K[j+3];
        }
        u = 1.0f / ((s0+s1) + (s2+s3));
    }
    #pragma unroll 1
    for (int it = 0; it < 19; ++it) {
        float s0=0.f, s1=0.f, s2=0.f, s3=0.f;            // C-update
        #pragma unroll
        for (int j = 0; j < 64; j += 4) {
            s0 = fmaf(KT[j  ], rlane(u, j  ), s0);
            s1 = fmaf(KT[j+1], rlane(u, j+1), s1);
            s2 = fmaf(KT[j+2], rlane(u, j+2), s2);
            s3 = fmaf(KT[j+3], rlane(u, j+3), s3);
        }
        v = 1.0f / ((s0+s1) + (s2+s3));
        s0=0.f; s1=0.f; s2=0.f; s3=0.f;                  // R-update
        #pragma unroll
        for (int j = 0; j < 64; j += 4) {
            s0 = fmaf(K[j  ], rlane(v, j  ), s0);
            s1 = fmaf(K[j+1], rlane(v, j+1), s1);
            s2 = fmaf(K[j+2], rlane(v, j+2), s2);
            s3 = fmaf(K[j+3], rlane(v, j+3), s3);
        }
        u = 1.0f / ((s0+s1) + (s2+s3));
    }
    {
        float s0=0.f, s1=0.f, s2=0.f, s3=0.f;            // C-update #20
        #pragma unroll
        for (int j = 0; j < 64; j += 4) {
            s0 = fmaf(KT[j  ], rlane(u, j  ), s0);
            s1 = fmaf(KT[j+1], rlane(u, j+1), s1);
            s2 = fmaf(KT[j+2], rlane(u, j+2), s2);
            s3 = fmaf(KT[j+3], rlane(u, j+3), s3);
        }
        v = 1.0f / ((s0+s1) + (s2+s3));
    }
    // final row softmax + expected position (u cancels in the row normalize)
    {
        float ss=0.f, sx=0.f, sy=0.f;
        #pragma unroll
        for (int j = 0; j < 64; ++j) {
            float pj = K[j] * rlane(v, j);
            ss += pj;
            sx = fmaf(pj, (float)(j & 7),  sx);
            sy = fmaf(pj, (float)(j >> 3), sy);
        }
        const float inv = 1.0f / ss;
        dispxA[t] = sx * inv - (float)(lane & 7);
        dispyA[t] = sy * inv - (float)(lane >> 3);
    }
    __syncthreads();

    // ---------------- phase 4: bilinear border warp over the 32x128 px strip ----------------
    #pragma unroll 2
    for (int rep = 0; rep < 16; ++rep) {
        const int p = rep * 256 + t;
        const int y = p >> 7;               // 0..31
        const int x = p & 127;              // 0..127
        const int m2 = ((y >> 2) << 3) + ((x & 31) >> 2);
        const int widx = (x >> 5) * 64 + m2;
        float gx = (float)(XB + x) + 4.0f * dispxA[widx];
        float gy = (float)(Y0 + y) + 4.0f * dispyA[widx];
        gx = fminf(fmaxf(gx, 0.0f), 255.0f);
        gy = fminf(fmaxf(gy, 0.0f), 255.0f);
        const float x0f = floorf(gx), y0f = floorf(gy);
        const float wxf = gx - x0f, wyf = gy - y0f;
        const int xi0 = (int)x0f, yi0 = (int)y0f;
        const int xi1 = min(xi0 + 1, 255), yi1 = min(yi0 + 1, 255);
        const float w00 = (1.f-wxf)*(1.f-wyf), w01 = wxf*(1.f-wyf);
        const float w10 = (1.f-wxf)*wyf,       w11 = wxf*wyf;
        const float* basep = z1 + (size_t)(b * 4) * 65536;
        #pragma unroll
        for (int c = 0; c < 4; ++c) {
            const float* pc = basep + c * 65536;
            const float v00 = pc[yi0*256 + xi0], v01 = pc[yi0*256 + xi1];
            const float v10 = pc[yi1*256 + xi0], v11 = pc[yi1*256 + xi1];
            out[((size_t)(b*4+c)*256 + (Y0+y))*256 + XB + x]
                = v00*w00 + v01*w01 + v10*w10 + v11*w11;
        }
    }
}

extern "C" void kernel_launch(void* const* d_in, const int* in_sizes, int n_in,
                              void* d_out, int out_size, void* d_ws, size_t ws_size,
                              hipStream_t stream) {
    (void)in_sizes; (void)n_in; (void)d_ws; (void)ws_size; (void)out_size;
    const float* z0 = (const float*)d_in[0];
    const float* z1 = (const float*)d_in[1];
    float* out = (float*)d_out;
    skw_kernel<<<dim3(256), dim3(256), 0, stream>>>(z0, z1, out);
}